// Round 5
// baseline (639.799 us; speedup 1.0000x reference)
//
#include <hip/hip_runtime.h>
#include <hip/hip_fp16.h>
#include <cmath>
#include <float.h>

// Problem constants
#define NUM_EMB 8192
#define DIM 256
#define HW 1024
#define N_TOK 32768
#define KSPLIT 4
#define KRANGE (NUM_EMB/KSPLIT)      // 2048 codes per split
#define OUT_ZQ_ELEMS 8388608

// coarse-pass capture: G' = 8192 * z.e ; d-margin = 2*0.4/8192 = 9.8e-5 vs
// required cell(3.05e-5)+2*eps_fp16(2.6e-5) = 5.7e-5 -> 1.7x safety (R4-validated)
#define CAP 16
#define MARGIN_GP 0.4f
#define SHIFT_GP  256.0f

// dist tiling
#define BM 128
#define BN 128
#define BK 32
#define TILES (KRANGE/BN)    // 16
#define CHUNKS (DIM/BK)      // 8

// ws layout (byte offsets)
#define WS_MSE    0
#define WS_COUNTS 64
#define WS_CNT    (WS_COUNTS + NUM_EMB*4)        // int[KSPLIT*N_TOK]
#define WS_MEMSET_END (WS_CNT + KSPLIT*N_TOK*4)
#define WS_Z2     WS_MEMSET_END                  // float[N_TOK]
#define WS_IDXF   (WS_Z2 + N_TOK*4)              // int[N_TOK]
#define WS_CANDI  (WS_IDXF + N_TOK*4)            // int[KSPLIT*N_TOK*CAP]

typedef _Float16 half8 __attribute__((ext_vector_type(8)));
typedef _Float16 half4v __attribute__((ext_vector_type(4)));
typedef float f32x4 __attribute__((ext_vector_type(4)));
typedef __attribute__((address_space(3))) void lds_void;
typedef __attribute__((address_space(1))) const void gbl_void;

// ---------------------------------------------------------------------------
// pack z -> fp16 token-major [n][c]  AND  z2[n] (numpy pairwise_sum(256)-exact)
__global__ __launch_bounds__(256) void vq_pack_z(
    const float* __restrict__ z, _Float16* __restrict__ zh, float* __restrict__ z2)
{
    __shared__ float zt[32][257];
    __shared__ float rr[32][16];     // [row][h*8 + j] partial strided sums
    int t = threadIdx.x;
    int n0 = blockIdx.x * 32;
    int b = n0 >> 10, hw0 = n0 & 1023;
    const float* zb = z + (size_t)b * DIM * HW + hw0;
    int tn = t & 31, tc = t >> 5;
    #pragma unroll 4
    for (int it = 0; it < 32; it++) {
        int c = it * 8 + tc;
        zt[tn][c] = zb[(size_t)c * HW + tn];
    }
    __syncthreads();
    // z2 partials: thread (row=tn2, j=tj) does both h-halves' strided chains
    int tn2 = t & 31, tj = t >> 5;
    #pragma unroll
    for (int h = 0; h < 2; h++) {
        float v0 = zt[tn2][h*128 + tj];
        float r = __fmul_rn(v0, v0);
        for (int i = 8; i < 128; i += 8) {
            float v = zt[tn2][h*128 + i + tj];
            r = __fadd_rn(r, __fmul_rn(v, v));
        }
        rr[tn2][h*8 + tj] = r;
    }
    // fp16 pack
    int row = t >> 3, seg = t & 7;
    half8 outv[4];
    #pragma unroll
    for (int q = 0; q < 4; q++)
        #pragma unroll
        for (int u = 0; u < 8; u++)
            outv[q][u] = (_Float16)zt[row][seg*32 + q*8 + u];
    half8* dst = (half8*)(zh + (size_t)(n0 + row) * DIM + seg * 32);
    #pragma unroll
    for (int q = 0; q < 4; q++) dst[q] = outv[q];
    __syncthreads();
    if (t < 32) {
        const float* rw = rr[t];
        float h0 = __fadd_rn(__fadd_rn(__fadd_rn(rw[0], rw[1]), __fadd_rn(rw[2], rw[3])),
                             __fadd_rn(__fadd_rn(rw[4], rw[5]), __fadd_rn(rw[6], rw[7])));
        float h1 = __fadd_rn(__fadd_rn(__fadd_rn(rw[8], rw[9]), __fadd_rn(rw[10], rw[11])),
                             __fadd_rn(__fadd_rn(rw[12], rw[13]), __fadd_rn(rw[14], rw[15])));
        z2[n0 + t] = __fadd_rn(h0, h1);
    }
}

// pack e: fp32 -> fp16 prescaled by 8192 (exact pow2; avoids fp16 denormals)
__global__ __launch_bounds__(256) void vq_pack_e(
    const float* __restrict__ emb, _Float16* __restrict__ eh)
{
    int i = blockIdx.x * 256 + threadIdx.x;
    float4 v = ((const float4*)emb)[i];
    half4v h;
    h[0] = (_Float16)(v.x * 8192.0f);
    h[1] = (_Float16)(v.y * 8192.0f);
    h[2] = (_Float16)(v.z * 8192.0f);
    h[3] = (_Float16)(v.w * 8192.0f);
    *(half4v*)(eh + (size_t)i * 4) = h;
}

// ---------------------------------------------------------------------------
// fp16 MFMA coarse pass, m97-style: 128x128 block tile, 4 waves (2x2), each
// wave 64x64 = 4x4 frags of 16x16x32; BK=32 double-buffered global_load_lds.
// Epilogue per 128-code tile: fused running-max + candidate append.
__global__ __launch_bounds__(256, 2) void vq_dist_kernel(
    const _Float16* __restrict__ zh, const _Float16* __restrict__ eh,
    int* __restrict__ cnt, int* __restrict__ candi)
{
    __shared__ _Float16 As[2][4096];   // 128 rows x 32 k, 16B-chunk swizzled
    __shared__ _Float16 Bs[2][4096];
    __shared__ float tmaxf[BM];        // running G'max + SHIFT per token row
    int t = threadIdx.x;
    int n0 = blockIdx.x * BM;
    int ks = blockIdx.y;
    int kbase = ks * KRANGE;
    int w = t >> 6, lane = t & 63;
    int wm = w >> 1, wn = w & 1;
    int lm = lane & 15, lq = lane >> 4;

    if (t < BM) tmaxf[t] = 0.f;

    // DMA staging map: thread t, rep r: chunk p = r*256+t; row m=p>>2;
    // k-octet q = ((p&3)-(m>>1))&3  (inverse of read swizzle)
    int pm[2], pq[2];
    #pragma unroll
    for (int r = 0; r < 2; r++) {
        int p = r * 256 + t;
        pm[r] = p >> 2;
        pq[r] = ((p & 3) - ((p >> 2) >> 1)) & 3;
    }
    // read offsets (halfs): A frag f: row m=wm*64+f*16+lm, octet q=lq
    int offA[4], offB[4];
    #pragma unroll
    for (int f = 0; f < 4; f++) {
        int mA = wm*64 + f*16 + lm;
        int mB = wn*64 + f*16 + lm;
        offA[f] = (mA*4 + ((lq + (mA>>1)) & 3)) * 8;
        offB[f] = (mB*4 + ((lq + (mB>>1)) & 3)) * 8;
    }

    // prologue: stage it=0 into buf 0
    #pragma unroll
    for (int r = 0; r < 2; r++) {
        __builtin_amdgcn_global_load_lds(
            (gbl_void*)(zh + (size_t)(n0 + pm[r]) * DIM + pq[r]*8),
            (lds_void*)((char*)&As[0][0] + r*4096 + w*1024), 16, 0, 0);
        __builtin_amdgcn_global_load_lds(
            (gbl_void*)(eh + (size_t)(kbase + pm[r]) * DIM + pq[r]*8),
            (lds_void*)((char*)&Bs[0][0] + r*4096 + w*1024), 16, 0, 0);
    }

    f32x4 acc[4][4];
    int buf = 0;
    for (int it = 0; it < TILES*CHUNKS; it++) {
        int tile = it >> 3, chunk = it & 7;
        if (chunk == 0) {
            #pragma unroll
            for (int i = 0; i < 4; i++)
                #pragma unroll
                for (int j = 0; j < 4; j++)
                    acc[i][j] = f32x4{0.f, 0.f, 0.f, 0.f};
        }
        __syncthreads();   // buf stores landed (vmcnt drain) + buf^1 reads done
        if (it + 1 < TILES*CHUNKS) {
            int nt = (it+1) >> 3, nc = (it+1) & 7;
            int cb = kbase + nt * BN;
            int k0 = nc * BK;
            #pragma unroll
            for (int r = 0; r < 2; r++) {
                __builtin_amdgcn_global_load_lds(
                    (gbl_void*)(zh + (size_t)(n0 + pm[r]) * DIM + k0 + pq[r]*8),
                    (lds_void*)((char*)&As[buf^1][0] + r*4096 + w*1024), 16, 0, 0);
                __builtin_amdgcn_global_load_lds(
                    (gbl_void*)(eh + (size_t)(cb + pm[r]) * DIM + k0 + pq[r]*8),
                    (lds_void*)((char*)&Bs[buf^1][0] + r*4096 + w*1024), 16, 0, 0);
            }
        }
        {
            half8 a[4], b[4];
            #pragma unroll
            for (int f = 0; f < 4; f++) a[f] = *(half8*)(&As[buf][0] + offA[f]);
            #pragma unroll
            for (int f = 0; f < 4; f++) b[f] = *(half8*)(&Bs[buf][0] + offB[f]);
            #pragma unroll
            for (int i = 0; i < 4; i++)
                #pragma unroll
                for (int j = 0; j < 4; j++)
                    acc[i][j] = __builtin_amdgcn_mfma_f32_16x16x32_f16(
                        a[i], b[j], acc[i][j], 0, 0, 0);
        }
        if (chunk == 7) {
            // epilogue for this 128-code tile
            int cb = kbase + tile * BN;
            float vms[4][4];
            // pass (a): per-row local max over 4 code-frags, update LDS running max
            #pragma unroll
            for (int i = 0; i < 4; i++) {
                int rb = wm*64 + i*16 + lq*4;        // rows rb..rb+3 (e)
                float4 tm4 = *(float4*)&tmaxf[rb];
                float tma[4] = {tm4.x, tm4.y, tm4.z, tm4.w};
                #pragma unroll
                for (int e = 0; e < 4; e++) {
                    float vm = fmaxf(fmaxf(acc[i][0][e], acc[i][1][e]),
                                     fmaxf(acc[i][2][e], acc[i][3][e])) + SHIFT_GP;
                    vms[i][e] = vm;
                    if (vm > tma[e])
                        atomicMax((int*)&tmaxf[rb + e], __float_as_int(vm));
                }
            }
            if (tile == 0) __syncthreads();   // fresh threshold for the cold start
            // pass (b): append candidates within margin (stale max -> superset, safe)
            #pragma unroll
            for (int i = 0; i < 4; i++) {
                int rb = wm*64 + i*16 + lq*4;
                float4 tm4 = *(float4*)&tmaxf[rb];
                float tma[4] = {tm4.x, tm4.y, tm4.z, tm4.w};
                #pragma unroll
                for (int e = 0; e < 4; e++) {
                    float cut = fmaxf(tma[e], vms[i][e]) - SHIFT_GP - MARGIN_GP;
                    #pragma unroll
                    for (int j = 0; j < 4; j++) {
                        if (acc[i][j][e] > cut) {
                            int token = n0 + rb + e;
                            int code  = cb + wn*64 + j*16 + lm;
                            int idx   = ks * N_TOK + token;
                            int slot  = atomicAdd(&cnt[idx], 1);
                            if (slot < CAP)
                                candi[(size_t)idx * CAP + slot] = code;
                        }
                    }
                }
            }
        }
        buf ^= 1;
    }
}

// ---------------------------------------------------------------------------
// Exact rescore: one wave per token, rescoring ALL appended candidates with the
// bit-exact R3 chain (ascending-c fmaf, d=fmaf(-2,acc,z2)); lexicographic min.
// Overflowed tokens -> full 8192-code scan (rare, provably-correct fallback).
__global__ __launch_bounds__(256) void vq_rescore_kernel(
    const float* __restrict__ z, const float* __restrict__ emb,
    const float* __restrict__ z2, const int* __restrict__ cnt,
    const int* __restrict__ candi, int* __restrict__ idxf)
{
    __shared__ float zl[4][DIM];
    int t = threadIdx.x, w = t >> 6, lane = t & 63;
    int n = blockIdx.x * 4 + w;
    int b = n >> 10, hw = n & 1023;
    const float* zp = z + (size_t)b * DIM * HW + hw;
    for (int c = lane; c < DIM; c += 64) zl[w][c] = zp[(size_t)c * HW];
    __syncthreads();
    float z2n = z2[n];
    int c4[KSPLIT];
    bool ovf = false;
    #pragma unroll
    for (int s = 0; s < KSPLIT; s++) {
        c4[s] = cnt[s * N_TOK + n];
        if (c4[s] > CAP) { ovf = true; c4[s] = CAP; }
    }
    int o1 = c4[0], o2 = o1 + c4[1], o3 = o2 + c4[2], nc = o3 + c4[3];
    unsigned long long best = ~0ULL;
    if (!ovf) {
        if (lane < nc) {
            int s  = (lane >= o1) + (lane >= o2) + (lane >= o3);
            int sl = lane - (s == 0 ? 0 : (s == 1 ? o1 : (s == 2 ? o2 : o3)));
            int code = candi[((size_t)s * N_TOK + n) * CAP + sl];
            float acc = 0.f;
            const float4* ep = (const float4*)(emb + (size_t)code * DIM);
            #pragma unroll 8
            for (int q = 0; q < 64; q++) {
                float4 e4 = ep[q];
                acc = fmaf(zl[w][q*4+0], e4.x, acc);
                acc = fmaf(zl[w][q*4+1], e4.y, acc);
                acc = fmaf(zl[w][q*4+2], e4.z, acc);
                acc = fmaf(zl[w][q*4+3], e4.w, acc);
            }
            float d = fmaf(-2.f, acc, z2n);
            best = ((unsigned long long)__float_as_uint(d) << 32) | (unsigned)code;
        }
    } else {
        for (int k = lane; k < NUM_EMB; k += 64) {
            float acc = 0.f;
            const float4* ep = (const float4*)(emb + (size_t)k * DIM);
            #pragma unroll 8
            for (int q = 0; q < 64; q++) {
                float4 e4 = ep[q];
                acc = fmaf(zl[w][q*4+0], e4.x, acc);
                acc = fmaf(zl[w][q*4+1], e4.y, acc);
                acc = fmaf(zl[w][q*4+2], e4.z, acc);
                acc = fmaf(zl[w][q*4+3], e4.w, acc);
            }
            float d = fmaf(-2.f, acc, z2n);
            unsigned long long key =
                ((unsigned long long)__float_as_uint(d) << 32) | (unsigned)k;
            if (key < best) best = key;
        }
    }
    #pragma unroll
    for (int o = 32; o > 0; o >>= 1) {
        unsigned long long ob = __shfl_xor(best, o);
        if (ob < best) best = ob;
    }
    if (lane == 0) idxf[n] = (int)(best & 0xffffffffu);
}

// ---------------------------------------------------------------------------
// Gather: z_q_st + indices out + MSE + histogram. 32 tokens per block.
#define GT 32
__global__ __launch_bounds__(256) void vq_gather_kernel(
    const float* __restrict__ z, const float* __restrict__ emb,
    const int* __restrict__ idxf,
    int* __restrict__ counts, double* __restrict__ mse_sum,
    float* __restrict__ out_zq, float* __restrict__ out_idx)
{
    __shared__ float zq[GT][DIM];
    __shared__ int sidx[GT];
    __shared__ double red[4];
    int t = threadIdx.x;
    int n0 = blockIdx.x * GT;

    if (t < GT) {
        int n = n0 + t;
        int bi = idxf[n];
        sidx[t] = bi;
        out_idx[n] = (float)bi;
        atomicAdd(&counts[bi], 1);
    }
    __syncthreads();

    int lane = t & 63, w = t >> 6;
    for (int m = w*8; m < w*8 + 8; m++) {
        int row = sidx[m];
        float4 v = *(const float4*)(emb + (size_t)row * DIM + lane * 4);
        int cb = (lane + m) & 63;
        *(float4*)&zq[m][cb * 4] = v;
    }
    __syncthreads();

    int n = t & 31, cc = t >> 5;
    int b = n0 >> 10;
    int hw = (n0 & 1023) + n;
    const float* zp = z + (size_t)b * DIM * HW + hw;
    float* op = out_zq + (size_t)b * DIM * HW + hw;
    float lsum = 0.f;
    #pragma unroll 4
    for (int i = 0; i < 32; i++) {
        int c = i*8 + cc;
        int cb = ((c >> 2) + n) & 63;
        float q = zq[n][cb*4 + (c & 3)];
        float zv = zp[(size_t)c * HW];
        op[(size_t)c * HW] = __fadd_rn(zv, __fsub_rn(q, zv));
        float d = zv - q;
        lsum = fmaf(d, d, lsum);
    }
    double ds = (double)lsum;
    #pragma unroll
    for (int off = 32; off > 0; off >>= 1)
        ds += __shfl_down(ds, off);
    if (lane == 0) red[w] = ds;
    __syncthreads();
    if (t == 0) atomicAdd(mse_sum, red[0] + red[1] + red[2] + red[3]);
}

// ---------------------------------------------------------------------------
__global__ __launch_bounds__(256) void vq_finalize_kernel(
    const double* __restrict__ mse_sum, const int* __restrict__ counts,
    float* __restrict__ out_scalars)
{
    __shared__ float red[4];
    int t = threadIdx.x;
    float local = 0.f;
    for (int k = t; k < NUM_EMB; k += 256) {
        int c = counts[k];
        if (c > 0) {
            float p = (float)c * (1.0f / (float)N_TOK);
            local += p * logf(p);
        }
    }
    int lane = t & 63, w = t >> 6;
    #pragma unroll
    for (int off = 32; off > 0; off >>= 1)
        local += __shfl_down(local, off);
    if (lane == 0) red[w] = local;
    __syncthreads();
    if (t == 0) {
        float s = red[0] + red[1] + red[2] + red[3];
        out_scalars[0] = 1.25f * (float)(*mse_sum * (1.0 / (double)OUT_ZQ_ELEMS));
        out_scalars[1] = expf(-s);
    }
}

// ---------------------------------------------------------------------------
extern "C" void kernel_launch(void* const* d_in, const int* in_sizes, int n_in,
                              void* d_out, int out_size, void* d_ws, size_t ws_size,
                              hipStream_t stream)
{
    const float* z   = (const float*)d_in[0];   // [32,256,32,32]
    const float* emb = (const float*)d_in[1];   // [8192,256]
    float* out = (float*)d_out;
    char* ws = (char*)d_ws;
    double* mse_sum = (double*)(ws + WS_MSE);
    int*    counts  = (int*)(ws + WS_COUNTS);
    int*    cnt     = (int*)(ws + WS_CNT);
    float*  z2      = (float*)(ws + WS_Z2);
    int*    idxf    = (int*)(ws + WS_IDXF);
    int*    candi   = (int*)(ws + WS_CANDI);

    // fp16 packs live in d_out's z_q region, overwritten later by gather
    _Float16* zh = (_Float16*)d_out;             // 16.78 MB
    _Float16* eh = (_Float16*)(out + 4194304);   //  4.19 MB

    hipMemsetAsync(d_ws, 0, WS_MEMSET_END, stream);

    vq_pack_e<<<NUM_EMB*DIM/4/256, 256, 0, stream>>>(emb, eh);
    vq_pack_z<<<N_TOK/32, 256, 0, stream>>>(z, zh, z2);
    vq_dist_kernel<<<dim3(N_TOK/BM, KSPLIT), 256, 0, stream>>>(zh, eh, cnt, candi);
    vq_rescore_kernel<<<N_TOK/4, 256, 0, stream>>>(z, emb, z2, cnt, candi, idxf);
    vq_gather_kernel<<<N_TOK/GT, 256, 0, stream>>>(z, emb, idxf, counts, mse_sum,
                                                   out, out + OUT_ZQ_ELEMS + 2);
    vq_finalize_kernel<<<1, 256, 0, stream>>>(mse_sum, counts, out + OUT_ZQ_ELEMS);
}